// Round 6
// baseline (309.260 us; speedup 1.0000x reference)
//
#include <hip/hip_runtime.h>
#include <hip/hip_bf16.h>

typedef unsigned short ushort_t;
typedef __attribute__((ext_vector_type(8))) short s16x8;
typedef __attribute__((ext_vector_type(4))) float f32x4;

__device__ inline unsigned short f2bf(float x) {
    unsigned u = __float_as_uint(x);
    return (unsigned short)((u + 0x7FFFu + ((u >> 16) & 1u)) >> 16);
}
__device__ inline float bflo(unsigned u) { return __uint_as_float(u << 16); }
__device__ inline float bfhi(unsigned u) { return __uint_as_float(u & 0xffff0000u); }

// ---------------------------------------------------------------------------
// convert_w: pack weights into MFMA B-fragment order (bf16). Zeroes counts8,
// U accumulator and Zg.
// ---------------------------------------------------------------------------
__device__ inline void pack_one(const float* __restrict__ W, int K, int N,
                                ushort_t* __restrict__ dst, int g) {
    int KT = K / 32;
    int nt = g / (KT * 64);
    int rem = g % (KT * 64);
    int kt = rem / 64, lane = rem % 64;
    int n = nt * 16 + (lane & 15);
    int kbase = kt * 32 + ((lane >> 4) << 3);
    ushort_t tmp[8];
#pragma unroll
    for (int j = 0; j < 8; ++j) tmp[j] = f2bf(W[(size_t)(kbase + j) * N + n]);
    uint4 pk;
    pk.x = tmp[0] | ((unsigned)tmp[1] << 16);
    pk.y = tmp[2] | ((unsigned)tmp[3] << 16);
    pk.z = tmp[4] | ((unsigned)tmp[5] << 16);
    pk.w = tmp[6] | ((unsigned)tmp[7] << 16);
    *(uint4*)&dst[(size_t)g * 8] = pk;
}

__global__ void convert_w(const float* __restrict__ Wn, const float* __restrict__ W1,
                          const float* __restrict__ Wu, const float* __restrict__ Wy1,
                          const float* __restrict__ Wa1,
                          ushort_t* __restrict__ Wnb, ushort_t* __restrict__ W1tb,
                          ushort_t* __restrict__ W1mb, ushort_t* __restrict__ Wub,
                          ushort_t* __restrict__ Wy1b, ushort_t* __restrict__ Wa1b,
                          int* __restrict__ counts8, float* __restrict__ U,
                          float* __restrict__ Zg, int N) {
    int t = blockIdx.x * 256 + threadIdx.x;
    if (t < 1024)       pack_one(Wn, 64, 128, Wnb, t);
    else if (t < 3072)  pack_one(W1, 128, 128, W1tb, t - 1024);
    else if (t < 5120)  pack_one(W1 + 128 * 128, 128, 128, W1mb, t - 3072);
    else if (t < 7168)  pack_one(Wu, 128, 128, Wub, t - 5120);
    else if (t < 8192)  pack_one(Wy1, 128, 64, Wy1b, t - 7168);
    else if (t < 9216)  pack_one(Wa1, 128, 64, Wa1b, t - 8192);
    int stride = gridDim.x * 256;
    for (int i = t; i < 8 * N; i += stride) counts8[i] = 0;
    float4 z4 = {0.f, 0.f, 0.f, 0.f};
    float4* U4 = (float4*)U;
    for (int i = t; i < 32 * N; i += stride) U4[i] = z4;   // 128N floats
    if (t == 0) Zg[0] = 0.f;
}

// ---------------------------------------------------------------------------
// encode_pq: 16-row M-tile per block, 4 waves split N-tiles. pos folded into
// P'/Q'. dst histogram at the end, 8-way privatized.
// ---------------------------------------------------------------------------
__global__ void encode_pq(const float* __restrict__ x, const ushort_t* __restrict__ Wnb,
                          const float* __restrict__ bn, const ushort_t* __restrict__ W1tb,
                          const ushort_t* __restrict__ W1mb, const float* __restrict__ b1,
                          const float* __restrict__ Wd, const float* __restrict__ pos,
                          ushort_t* __restrict__ hb, ushort_t* __restrict__ P,
                          ushort_t* __restrict__ Q, const int* __restrict__ dst,
                          int* __restrict__ counts8, int nrows, int E) {
    __shared__ ushort_t ldsH[16 * 136];
    __shared__ float ldsWd[384];
    int t = threadIdx.x;
    for (int i = t; i < 384; i += 256) ldsWd[i] = Wd[i];
    int w = t >> 6, lane = t & 63;
    int c = lane & 15, q = lane >> 4;
    int r0 = blockIdx.x * 16;
    int rowA = r0 + c; if (rowA >= nrows) rowA = nrows - 1;

    s16x8 xa[2];
#pragma unroll
    for (int kt = 0; kt < 2; ++kt) {
        const float* xp = &x[(size_t)rowA * 64 + kt * 32 + q * 8];
        float4 v0 = *(const float4*)xp;
        float4 v1 = *(const float4*)(xp + 4);
        s16x8 a;
        a[0] = (short)f2bf(v0.x); a[1] = (short)f2bf(v0.y);
        a[2] = (short)f2bf(v0.z); a[3] = (short)f2bf(v0.w);
        a[4] = (short)f2bf(v1.x); a[5] = (short)f2bf(v1.y);
        a[6] = (short)f2bf(v1.z); a[7] = (short)f2bf(v1.w);
        xa[kt] = a;
    }
#pragma unroll
    for (int half = 0; half < 2; ++half) {
        int nt = w + half * 4;
        f32x4 acc = {0.f, 0.f, 0.f, 0.f};
#pragma unroll
        for (int kt = 0; kt < 2; ++kt) {
            s16x8 b = *(const s16x8*)&Wnb[((nt * 2 + kt) * 64 + lane) * 8];
            acc = __builtin_amdgcn_mfma_f32_16x16x32_bf16(xa[kt], b, acc, 0, 0, 0);
        }
        float bi = bn[nt * 16 + c];
#pragma unroll
        for (int r = 0; r < 4; ++r) {
            int row = r0 + q * 4 + r;
            ushort_t hv = f2bf(acc[r] + bi);
            ldsH[(q * 4 + r) * 136 + nt * 16 + c] = hv;
            if (row < nrows) hb[(size_t)row * 128 + nt * 16 + c] = hv;
        }
    }
    __syncthreads();
    s16x8 ha[4];
#pragma unroll
    for (int kt = 0; kt < 4; ++kt)
        ha[kt] = *(const s16x8*)&ldsH[c * 136 + kt * 32 + q * 8];
    float prx[4], pry[4], prz[4];
#pragma unroll
    for (int r = 0; r < 4; ++r) {
        int row = r0 + q * 4 + r;
        int rowc = (row < nrows) ? row : (nrows - 1);
        prx[r] = pos[rowc * 3];
        pry[r] = pos[rowc * 3 + 1];
        prz[r] = pos[rowc * 3 + 2];
    }
#pragma unroll
    for (int half = 0; half < 2; ++half) {
        int nt = w + half * 4;
        f32x4 pa = {0.f, 0.f, 0.f, 0.f}, qa = pa;
#pragma unroll
        for (int kt = 0; kt < 4; ++kt) {
            s16x8 bp = *(const s16x8*)&W1tb[((nt * 4 + kt) * 64 + lane) * 8];
            s16x8 bq = *(const s16x8*)&W1mb[((nt * 4 + kt) * 64 + lane) * 8];
            pa = __builtin_amdgcn_mfma_f32_16x16x32_bf16(ha[kt], bp, pa, 0, 0, 0);
            qa = __builtin_amdgcn_mfma_f32_16x16x32_bf16(ha[kt], bq, qa, 0, 0, 0);
        }
        int col = nt * 16 + c;
        float bi = b1[col];
        float wd0 = ldsWd[col], wd1 = ldsWd[128 + col], wd2 = ldsWd[256 + col];
#pragma unroll
        for (int r = 0; r < 4; ++r) {
            int row = r0 + q * 4 + r;
            if (row < nrows) {
                float pd = prx[r] * wd0 + pry[r] * wd1 + prz[r] * wd2;
                P[(size_t)row * 128 + col] = f2bf(pa[r] + bi + pd);
                Q[(size_t)row * 128 + col] = f2bf(qa[r] - pd);
            }
        }
    }
    int* myc = counts8 + (size_t)(blockIdx.x & 7) * nrows;
    for (int e = blockIdx.x * 256 + t; e < E; e += gridDim.x * 256)
        atomicAdd(&myc[dst[e]], 1);
}

// ---------------------------------------------------------------------------
// CSR scan: scan1 (merges 8 privatized bins) + scan_add (offs -> cursor init)
// ---------------------------------------------------------------------------
__global__ void scan1(const int* __restrict__ counts8, int* __restrict__ offs,
                      int* __restrict__ partials, int N) {
    __shared__ int sm[256];
    int i = blockIdx.x * 256 + threadIdx.x;
    int v = 0;
    if (i < N) {
#pragma unroll
        for (int j = 0; j < 8; ++j) v += counts8[(size_t)j * N + i];
    }
    sm[threadIdx.x] = v; __syncthreads();
    for (int off = 1; off < 256; off <<= 1) {
        int add = (threadIdx.x >= off) ? sm[threadIdx.x - off] : 0;
        __syncthreads();
        sm[threadIdx.x] += add;
        __syncthreads();
    }
    if (i < N) offs[i] = sm[threadIdx.x] - v;
    if (threadIdx.x == 255) partials[blockIdx.x] = sm[255];
}

__global__ void scan_add(int* __restrict__ offs, int* __restrict__ cursor,
                         const int* __restrict__ partials, int nb, int N) {
    __shared__ int sm[256];
    int t = threadIdx.x;
    sm[t] = (t < nb && t < blockIdx.x) ? partials[t] : 0;
    __syncthreads();
    for (int off = 128; off > 0; off >>= 1) {
        if (t < off) sm[t] += sm[t + off];
        __syncthreads();
    }
    int basev = sm[0];
    int i = blockIdx.x * 256 + t;
    if (i < N) {
        int v = offs[i] + basev;
        offs[i] = v;
        cursor[i] = v;
    }
}

// ---------------------------------------------------------------------------
// scatter_edges: put each edge into its dst-CSR slot as (src, dst).
// ---------------------------------------------------------------------------
__global__ void scatter_edges(const int* __restrict__ src, const int* __restrict__ dst,
                              int* __restrict__ cursor, int2* __restrict__ csr, int E) {
    int e = blockIdx.x * 256 + threadIdx.x;
    if (e < E) {
        int s = src[e], d = dst[e];
        int p = atomicAdd(&cursor[d], 1);
        csr[p] = make_int2(s, d);
    }
}

// ---------------------------------------------------------------------------
// edge_fused: score + softmax-weighted aggregation in ONE pass over dst-sorted
// CSR. Scores are O(1) for this model (|s| << 1), so raw exp(s) is safe:
//   U[d] = sum_{e: dst=d} exp(s_e) * h[src_e],  Z = sum_e exp(s_e)
// and aggr = U/Z identically equals softmax aggregation.
// Each 16-lane group owns 32 CONTIGUOUS slots; dst-segments interior to the
// run flush with plain coalesced stores, run-boundary segments with atomicAdd.
// Eliminates: score materialization, global-max pass, and the entire second
// random-gather kernel phase.
// ---------------------------------------------------------------------------
__global__ __launch_bounds__(256, 4)
void edge_fused(const ushort_t* __restrict__ P, const ushort_t* __restrict__ Q,
                const ushort_t* __restrict__ hb,
                const float* __restrict__ W2, const float* __restrict__ b2,
                const int2* __restrict__ csr,
                float* __restrict__ U, float* __restrict__ Zg, int E) {
    __shared__ float wsh[128];
    __shared__ float zsh[4];
    int t = threadIdx.x;
    if (t < 128) wsh[t] = W2[t];
    __syncthreads();
    int w = t >> 6, lane = t & 63;
    int g = lane >> 4, c = lane & 15;
    float wv[8];
#pragma unroll
    for (int j = 0; j < 8; ++j) wv[j] = wsh[c * 8 + j];
    float b2v = b2[0];
    int base = blockIdx.x * 512 + w * 128 + g * 32;   // this group's 32-slot run
    float acc[8] = {0.f, 0.f, 0.f, 0.f, 0.f, 0.f, 0.f, 0.f};
    float zacc = 0.f;
    int cur = -1, first_dst = -1;
    bool done = false;
    for (int bt = 0; bt < 8 && !done; ++bt) {
        int sa[4], da[4];
        uint4 qr[4], hr[4], pr[4];
        // 1) csr entries (group-uniform broadcast, coalesced across groups)
#pragma unroll
        for (int it = 0; it < 4; ++it) {
            int p = base + bt * 4 + it;
            int pp = (p < E) ? p : (E - 1);
            int2 v = csr[pp];
            sa[it] = v.x; da[it] = v.y;
        }
        // 2) issue all 12 row loads back-to-back (Q,hb random; P L1-hot)
#pragma unroll
        for (int it = 0; it < 4; ++it) {
            qr[it] = *(const uint4*)&Q[(size_t)sa[it] * 128 + c * 8];
            hr[it] = *(const uint4*)&hb[(size_t)sa[it] * 128 + c * 8];
            pr[it] = *(const uint4*)&P[(size_t)da[it] * 128 + c * 8];
        }
        // 3) score + accumulate, slots strictly ascending
#pragma unroll
        for (int it = 0; it < 4; ++it) {
            int p = base + bt * 4 + it;
            if (p >= E) { done = true; break; }
            unsigned pw[4] = {pr[it].x, pr[it].y, pr[it].z, pr[it].w};
            unsigned qw[4] = {qr[it].x, qr[it].y, qr[it].z, qr[it].w};
            float v = 0.f;
#pragma unroll
            for (int jj = 0; jj < 4; ++jj) {
                float pe = bflo(pw[jj]) + bflo(qw[jj]);
                float po = bfhi(pw[jj]) + bfhi(qw[jj]);
                v += fmaxf(pe, 0.f) * wv[2 * jj] + fmaxf(po, 0.f) * wv[2 * jj + 1];
            }
#pragma unroll
            for (int off = 1; off < 16; off <<= 1) v += __shfl_xor(v, off, 64);
            float ev = __expf(v + b2v);
            if (da[it] != cur) {
                if (cur >= 0) {
                    float* up = &U[(size_t)cur * 128 + c * 8];
                    if (cur == first_dst) {    // may extend into previous run
#pragma unroll
                        for (int j = 0; j < 8; ++j) atomicAdd(&up[j], acc[j]);
                    } else {                   // interior: whole segment is ours
                        float4 a0 = {acc[0], acc[1], acc[2], acc[3]};
                        float4 a1 = {acc[4], acc[5], acc[6], acc[7]};
                        *(float4*)up = a0;
                        *(float4*)(up + 4) = a1;
                    }
#pragma unroll
                    for (int j = 0; j < 8; ++j) acc[j] = 0.f;
                }
                if (cur < 0) first_dst = da[it];
                cur = da[it];
            }
            unsigned hw[4] = {hr[it].x, hr[it].y, hr[it].z, hr[it].w};
            acc[0] += bflo(hw[0]) * ev; acc[1] += bfhi(hw[0]) * ev;
            acc[2] += bflo(hw[1]) * ev; acc[3] += bfhi(hw[1]) * ev;
            acc[4] += bflo(hw[2]) * ev; acc[5] += bfhi(hw[2]) * ev;
            acc[6] += bflo(hw[3]) * ev; acc[7] += bfhi(hw[3]) * ev;
            zacc += ev;
        }
    }
    // final flush: last dst may extend into the next run -> always atomic
    if (cur >= 0) {
        float* up = &U[(size_t)cur * 128 + c * 8];
#pragma unroll
        for (int j = 0; j < 8; ++j) atomicAdd(&up[j], acc[j]);
    }
    // Z: one value per group (lanes hold identical zacc); block sum -> atomic
    float zv = (c == 0) ? zacc : 0.f;
#pragma unroll
    for (int off = 1; off < 64; off <<= 1) zv += __shfl_xor(zv, off, 64);
    if (lane == 0) zsh[w] = zv;
    __syncthreads();
    if (t == 0) atomicAdd(Zg, zsh[0] + zsh[1] + zsh[2] + zsh[3]);
}

// ---------------------------------------------------------------------------
// node_upd: blocks [0,nbG): molf = (U * 1/Z) @ Wu + bu — fully streaming.
// Blocks [nbG,..): fused prediction heads (unchanged).
// ---------------------------------------------------------------------------
__global__ void node_upd(const float* __restrict__ U, const float* __restrict__ Zg,
                         const ushort_t* __restrict__ Wub, const float* __restrict__ bu,
                         float* __restrict__ molf, int N, int nbG,
                         const float* __restrict__ rx, const float* __restrict__ tx,
                         const ushort_t* __restrict__ Wnb, const float* __restrict__ bn,
                         const ushort_t* __restrict__ Wy1b, const float* __restrict__ by1,
                         const float* __restrict__ Wy2, const float* __restrict__ by2,
                         const ushort_t* __restrict__ Wa1b, const float* __restrict__ ba1,
                         const float* __restrict__ Wa2, const float* __restrict__ ba2,
                         float* __restrict__ out, int nb1, int NR, int NT) {
    int t = threadIdx.x;
    int w = t >> 6, lane = t & 63;
    int c = lane & 15, q = lane >> 4;

    if (blockIdx.x < nbG) {
        __shared__ ushort_t ldsA[16 * 136];
        float inv = 1.f / Zg[0];
        int r0 = blockIdx.x * 16;
        {
            int idx = t * 8;            // 2048 f32 = 16 rows x 128 cols
            int row = idx >> 7;
            int col = idx & 127;
            int rr = r0 + row; if (rr >= N) rr = N - 1;
            const float* up = &U[(size_t)rr * 128 + col];
            float4 a = *(const float4*)up;
            float4 b = *(const float4*)(up + 4);
            uint4 pk;
            pk.x = f2bf(a.x * inv) | ((unsigned)f2bf(a.y * inv) << 16);
            pk.y = f2bf(a.z * inv) | ((unsigned)f2bf(a.w * inv) << 16);
            pk.z = f2bf(b.x * inv) | ((unsigned)f2bf(b.y * inv) << 16);
            pk.w = f2bf(b.z * inv) | ((unsigned)f2bf(b.w * inv) << 16);
            *(uint4*)&ldsA[row * 136 + col] = pk;
        }
        __syncthreads();
        int ntA = w, ntB = w + 4;
        f32x4 acc0 = {0.f, 0.f, 0.f, 0.f}, acc1 = acc0;
#pragma unroll
        for (int kt = 0; kt < 4; ++kt) {
            s16x8 av = *(const s16x8*)&ldsA[c * 136 + kt * 32 + q * 8];
            s16x8 b0 = *(const s16x8*)&Wub[((ntA * 4 + kt) * 64 + lane) * 8];
            s16x8 b1 = *(const s16x8*)&Wub[((ntB * 4 + kt) * 64 + lane) * 8];
            acc0 = __builtin_amdgcn_mfma_f32_16x16x32_bf16(av, b0, acc0, 0, 0, 0);
            acc1 = __builtin_amdgcn_mfma_f32_16x16x32_bf16(av, b1, acc1, 0, 0, 0);
        }
        float bi0 = bu[ntA * 16 + c], bi1 = bu[ntB * 16 + c];
#pragma unroll
        for (int r = 0; r < 4; ++r) {
            int row = r0 + q * 4 + r;
            if (row < N) {
                molf[(size_t)row * 128 + ntA * 16 + c] = acc0[r] + bi0;
                molf[(size_t)row * 128 + ntB * 16 + c] = acc1[r] + bi1;
            }
        }
    } else {
        // ------------------ prediction heads ------------------
        __shared__ ushort_t ldsX[16 * 72];
        __shared__ ushort_t ldsB[16 * 136];
        __shared__ float part[64];
        int blk = blockIdx.x - nbG;
        const float* x; const ushort_t* W1b; const float* b1; const float* W2; const float* b2;
        float* o; int r0, nrows;
        if (blk < nb1) { x = rx; W1b = Wy1b; b1 = by1; W2 = Wy2; b2 = by2; o = out; r0 = blk * 16; nrows = NR; }
        else { x = tx; W1b = Wa1b; b1 = ba1; W2 = Wa2; b2 = ba2; o = out + NR; r0 = (blk - nb1) * 16; nrows = NT; }
        {
            int row = t >> 4, c4 = (t & 15) * 4;
            float4 v = *(const float4*)&x[(size_t)(r0 + row) * 64 + c4];
            uint2 pk;
            pk.x = f2bf(v.x) | ((unsigned)f2bf(v.y) << 16);
            pk.y = f2bf(v.z) | ((unsigned)f2bf(v.w) << 16);
            *(uint2*)&ldsX[row * 72 + c4] = pk;
        }
        __syncthreads();
        {
            int ntA = w, ntB = w + 4;
            f32x4 acc0 = {0.f, 0.f, 0.f, 0.f}, acc1 = acc0;
#pragma unroll
            for (int kt = 0; kt < 2; ++kt) {
                s16x8 a = *(const s16x8*)&ldsX[c * 72 + kt * 32 + q * 8];
                s16x8 b0 = *(const s16x8*)&Wnb[((ntA * 2 + kt) * 64 + lane) * 8];
                s16x8 b1v = *(const s16x8*)&Wnb[((ntB * 2 + kt) * 64 + lane) * 8];
                acc0 = __builtin_amdgcn_mfma_f32_16x16x32_bf16(a, b0, acc0, 0, 0, 0);
                acc1 = __builtin_amdgcn_mfma_f32_16x16x32_bf16(a, b1v, acc1, 0, 0, 0);
            }
            float bi0 = bn[ntA * 16 + c], bi1 = bn[ntB * 16 + c];
#pragma unroll
            for (int r = 0; r < 4; ++r) {
                int row = q * 4 + r;
                ldsB[row * 136 + ntA * 16 + c] = f2bf(acc0[r] + bi0);
                ldsB[row * 136 + ntB * 16 + c] = f2bf(acc1[r] + bi1);
            }
        }
        __syncthreads();
        {
            f32x4 acc = {0.f, 0.f, 0.f, 0.f};
#pragma unroll
            for (int kt = 0; kt < 4; ++kt) {
                s16x8 a = *(const s16x8*)&ldsB[c * 136 + kt * 32 + q * 8];
                s16x8 b0 = *(const s16x8*)&W1b[((w * 4 + kt) * 64 + lane) * 8];
                acc = __builtin_amdgcn_mfma_f32_16x16x32_bf16(a, b0, acc, 0, 0, 0);
            }
            float bi = b1[w * 16 + c], w2v = W2[w * 16 + c];
#pragma unroll
            for (int r = 0; r < 4; ++r) {
                float u = fmaxf(acc[r] + bi, 0.f) * w2v;
#pragma unroll
                for (int mm = 1; mm < 16; mm <<= 1) u += __shfl_xor(u, mm, 64);
                if (c == 0) part[w * 16 + q * 4 + r] = u;
            }
        }
        __syncthreads();
        if (t < 16) {
            int row = r0 + t;
            if (row < nrows)
                o[row] = part[t] + part[16 + t] + part[32 + t] + part[48 + t] + b2[0];
        }
    }
}

extern "C" void kernel_launch(void* const* d_in, const int* in_sizes, int n_in,
                              void* d_out, int out_size, void* d_ws, size_t ws_size,
                              hipStream_t stream) {
    const float* mol_x      = (const float*)d_in[0];
    const float* pos        = (const float*)d_in[1];
    const float* reaction_x = (const float*)d_in[2];
    const float* target_x   = (const float*)d_in[3];
    const int*   ei         = (const int*)d_in[4];
    const float* W_node = (const float*)d_in[5];
    const float* b_node = (const float*)d_in[6];
    const float* W_att1 = (const float*)d_in[7];
    const float* b_att1 = (const float*)d_in[8];
    const float* W_att2 = (const float*)d_in[9];
    const float* b_att2 = (const float*)d_in[10];
    const float* W_upd  = (const float*)d_in[11];
    const float* b_upd  = (const float*)d_in[12];
    const float* Wy1 = (const float*)d_in[13];
    const float* by1 = (const float*)d_in[14];
    const float* Wy2 = (const float*)d_in[15];
    const float* by2 = (const float*)d_in[16];
    const float* Wa1 = (const float*)d_in[17];
    const float* ba1 = (const float*)d_in[18];
    const float* Wa2 = (const float*)d_in[19];
    const float* ba2 = (const float*)d_in[20];

    int N  = in_sizes[0] / 64;
    int E  = in_sizes[4] / 2;
    int NR = in_sizes[2] / 64;
    int NT = in_sizes[3] / 64;

    float* out = (float*)d_out;

    int nbG = (N + 15) / 16;     // node tiles
    int nbH = (NR + NT) / 16;    // head blocks
    int nbB = (E + 511) / 512;   // edge_fused blocks (512 slots/block)

    // ws layout
    char* wp = (char*)d_ws;
    ushort_t* hb = (ushort_t*)wp;  wp += (size_t)N * 128 * 2;
    ushort_t* Qb = (ushort_t*)wp;  wp += (size_t)N * 128 * 2;
    float* U     = (float*)wp;     wp += (size_t)N * 128 * 4;
    float* Zg    = (float*)wp;     wp += 256;
    int* counts8 = (int*)wp;       wp += (size_t)8 * N * 4;
    int* offs    = (int*)wp;       wp += (size_t)N * 4;
    int* cursor  = (int*)wp;       wp += (size_t)N * 4;
    int* partials= (int*)wp;       wp += 256 * 4;
    int2* csr    = (int2*)wp;      wp += (size_t)E * 8;
    ushort_t* Wnb  = (ushort_t*)wp; wp += 8192 * 2;
    ushort_t* W1tb = (ushort_t*)wp; wp += 16384 * 2;
    ushort_t* W1mb = (ushort_t*)wp; wp += 16384 * 2;
    ushort_t* Wub  = (ushort_t*)wp; wp += 16384 * 2;
    ushort_t* Wy1b = (ushort_t*)wp; wp += 8192 * 2;
    ushort_t* Wa1b = (ushort_t*)wp; wp += 8192 * 2;
    // P lives in the mol_feats output region (dead before node_upd writes it)
    ushort_t* Pb = (ushort_t*)(out + NR + NT);
    float* molf  = out + NR + NT;

    const int* srcp = ei;
    const int* dstp = ei + E;
    int nbN = (N + 255) / 256;
    int nbS = (E + 255) / 256;
    int nbC = 784;               // convert_w grid (fast U zeroing)

    convert_w<<<nbC, 256, 0, stream>>>(W_node, W_att1, W_upd, Wy1, Wa1,
                                       Wnb, W1tb, W1mb, Wub, Wy1b, Wa1b,
                                       counts8, U, Zg, N);
    encode_pq<<<(N + 15) / 16, 256, 0, stream>>>(mol_x, Wnb, b_node, W1tb, W1mb, b_att1,
                                                 W_att1 + 256 * 128, pos,
                                                 hb, Pb, Qb, dstp, counts8, N, E);
    scan1<<<nbN, 256, 0, stream>>>(counts8, offs, partials, N);
    scan_add<<<nbN, 256, 0, stream>>>(offs, cursor, partials, nbN, N);
    scatter_edges<<<nbS, 256, 0, stream>>>(srcp, dstp, cursor, csr, E);
    edge_fused<<<nbB, 256, 0, stream>>>(Pb, Qb, hb, W_att2, b_att2,
                                        csr, U, Zg, E);
    node_upd<<<nbG + nbH, 256, 0, stream>>>(U, Zg, Wub, b_upd, molf, N, nbG,
                                            reaction_x, target_x, Wnb, b_node,
                                            Wy1b, by1, Wy2, by2, Wa1b, ba1, Wa2, ba2,
                                            out, NR / 16, NR, NT);
}

// Round 7
// 250.761 us; speedup vs baseline: 1.2333x; 1.2333x over previous
//
#include <hip/hip_runtime.h>
#include <hip/hip_bf16.h>

typedef unsigned short ushort_t;
typedef __attribute__((ext_vector_type(8))) short s16x8;
typedef __attribute__((ext_vector_type(4))) float f32x4;

__device__ inline unsigned short f2bf(float x) {
    unsigned u = __float_as_uint(x);
    return (unsigned short)((u + 0x7FFFu + ((u >> 16) & 1u)) >> 16);
}
__device__ inline float bflo(unsigned u) { return __uint_as_float(u << 16); }
__device__ inline float bfhi(unsigned u) { return __uint_as_float(u & 0xffff0000u); }

// ---------------------------------------------------------------------------
// convert_w: pack weights into MFMA B-fragment order (bf16). Zeroes counts8, Zg.
// ---------------------------------------------------------------------------
__device__ inline void pack_one(const float* __restrict__ W, int K, int N,
                                ushort_t* __restrict__ dst, int g) {
    int KT = K / 32;
    int nt = g / (KT * 64);
    int rem = g % (KT * 64);
    int kt = rem / 64, lane = rem % 64;
    int n = nt * 16 + (lane & 15);
    int kbase = kt * 32 + ((lane >> 4) << 3);
    ushort_t tmp[8];
#pragma unroll
    for (int j = 0; j < 8; ++j) tmp[j] = f2bf(W[(size_t)(kbase + j) * N + n]);
    uint4 pk;
    pk.x = tmp[0] | ((unsigned)tmp[1] << 16);
    pk.y = tmp[2] | ((unsigned)tmp[3] << 16);
    pk.z = tmp[4] | ((unsigned)tmp[5] << 16);
    pk.w = tmp[6] | ((unsigned)tmp[7] << 16);
    *(uint4*)&dst[(size_t)g * 8] = pk;
}

__global__ void convert_w(const float* __restrict__ Wn, const float* __restrict__ W1,
                          const float* __restrict__ Wu, const float* __restrict__ Wy1,
                          const float* __restrict__ Wa1,
                          ushort_t* __restrict__ Wnb, ushort_t* __restrict__ W1tb,
                          ushort_t* __restrict__ W1mb, ushort_t* __restrict__ Wub,
                          ushort_t* __restrict__ Wy1b, ushort_t* __restrict__ Wa1b,
                          int* __restrict__ counts8, float* __restrict__ Zg, int N) {
    int t = blockIdx.x * 256 + threadIdx.x;
    if (t < 1024)       pack_one(Wn, 64, 128, Wnb, t);
    else if (t < 3072)  pack_one(W1, 128, 128, W1tb, t - 1024);
    else if (t < 5120)  pack_one(W1 + 128 * 128, 128, 128, W1mb, t - 3072);
    else if (t < 7168)  pack_one(Wu, 128, 128, Wub, t - 5120);
    else if (t < 8192)  pack_one(Wy1, 128, 64, Wy1b, t - 7168);
    else if (t < 9216)  pack_one(Wa1, 128, 64, Wa1b, t - 8192);
    int stride = gridDim.x * 256;
    for (int i = t; i < 8 * N; i += stride) counts8[i] = 0;
    if (t == 0) Zg[0] = 0.f;
}

// ---------------------------------------------------------------------------
// encode_pq: 16-row M-tile per block, 4 waves split N-tiles. pos folded into
// P'/Q'. dst histogram at the end, 8-way privatized.
// ---------------------------------------------------------------------------
__global__ void encode_pq(const float* __restrict__ x, const ushort_t* __restrict__ Wnb,
                          const float* __restrict__ bn, const ushort_t* __restrict__ W1tb,
                          const ushort_t* __restrict__ W1mb, const float* __restrict__ b1,
                          const float* __restrict__ Wd, const float* __restrict__ pos,
                          ushort_t* __restrict__ hb, ushort_t* __restrict__ P,
                          ushort_t* __restrict__ Q, const int* __restrict__ dst,
                          int* __restrict__ counts8, int nrows, int E) {
    __shared__ ushort_t ldsH[16 * 136];
    __shared__ float ldsWd[384];
    int t = threadIdx.x;
    for (int i = t; i < 384; i += 256) ldsWd[i] = Wd[i];
    int w = t >> 6, lane = t & 63;
    int c = lane & 15, q = lane >> 4;
    int r0 = blockIdx.x * 16;
    int rowA = r0 + c; if (rowA >= nrows) rowA = nrows - 1;

    s16x8 xa[2];
#pragma unroll
    for (int kt = 0; kt < 2; ++kt) {
        const float* xp = &x[(size_t)rowA * 64 + kt * 32 + q * 8];
        float4 v0 = *(const float4*)xp;
        float4 v1 = *(const float4*)(xp + 4);
        s16x8 a;
        a[0] = (short)f2bf(v0.x); a[1] = (short)f2bf(v0.y);
        a[2] = (short)f2bf(v0.z); a[3] = (short)f2bf(v0.w);
        a[4] = (short)f2bf(v1.x); a[5] = (short)f2bf(v1.y);
        a[6] = (short)f2bf(v1.z); a[7] = (short)f2bf(v1.w);
        xa[kt] = a;
    }
#pragma unroll
    for (int half = 0; half < 2; ++half) {
        int nt = w + half * 4;
        f32x4 acc = {0.f, 0.f, 0.f, 0.f};
#pragma unroll
        for (int kt = 0; kt < 2; ++kt) {
            s16x8 b = *(const s16x8*)&Wnb[((nt * 2 + kt) * 64 + lane) * 8];
            acc = __builtin_amdgcn_mfma_f32_16x16x32_bf16(xa[kt], b, acc, 0, 0, 0);
        }
        float bi = bn[nt * 16 + c];
#pragma unroll
        for (int r = 0; r < 4; ++r) {
            int row = r0 + q * 4 + r;
            ushort_t hv = f2bf(acc[r] + bi);
            ldsH[(q * 4 + r) * 136 + nt * 16 + c] = hv;
            if (row < nrows) hb[(size_t)row * 128 + nt * 16 + c] = hv;
        }
    }
    __syncthreads();
    s16x8 ha[4];
#pragma unroll
    for (int kt = 0; kt < 4; ++kt)
        ha[kt] = *(const s16x8*)&ldsH[c * 136 + kt * 32 + q * 8];
    float prx[4], pry[4], prz[4];
#pragma unroll
    for (int r = 0; r < 4; ++r) {
        int row = r0 + q * 4 + r;
        int rowc = (row < nrows) ? row : (nrows - 1);
        prx[r] = pos[rowc * 3];
        pry[r] = pos[rowc * 3 + 1];
        prz[r] = pos[rowc * 3 + 2];
    }
#pragma unroll
    for (int half = 0; half < 2; ++half) {
        int nt = w + half * 4;
        f32x4 pa = {0.f, 0.f, 0.f, 0.f}, qa = pa;
#pragma unroll
        for (int kt = 0; kt < 4; ++kt) {
            s16x8 bp = *(const s16x8*)&W1tb[((nt * 4 + kt) * 64 + lane) * 8];
            s16x8 bq = *(const s16x8*)&W1mb[((nt * 4 + kt) * 64 + lane) * 8];
            pa = __builtin_amdgcn_mfma_f32_16x16x32_bf16(ha[kt], bp, pa, 0, 0, 0);
            qa = __builtin_amdgcn_mfma_f32_16x16x32_bf16(ha[kt], bq, qa, 0, 0, 0);
        }
        int col = nt * 16 + c;
        float bi = b1[col];
        float wd0 = ldsWd[col], wd1 = ldsWd[128 + col], wd2 = ldsWd[256 + col];
#pragma unroll
        for (int r = 0; r < 4; ++r) {
            int row = r0 + q * 4 + r;
            if (row < nrows) {
                float pd = prx[r] * wd0 + pry[r] * wd1 + prz[r] * wd2;
                P[(size_t)row * 128 + col] = f2bf(pa[r] + bi + pd);
                Q[(size_t)row * 128 + col] = f2bf(qa[r] - pd);
            }
        }
    }
    int* myc = counts8 + (size_t)(blockIdx.x & 7) * nrows;
    for (int e = blockIdx.x * 256 + t; e < E; e += gridDim.x * 256)
        atomicAdd(&myc[dst[e]], 1);
}

// ---------------------------------------------------------------------------
// CSR scan: scan1 (merges 8 privatized bins -> counts) + scan_add
// ---------------------------------------------------------------------------
__global__ void scan1(const int* __restrict__ counts8, int* __restrict__ counts,
                      int* __restrict__ offs, int* __restrict__ partials, int N) {
    __shared__ int sm[256];
    int i = blockIdx.x * 256 + threadIdx.x;
    int v = 0;
    if (i < N) {
#pragma unroll
        for (int j = 0; j < 8; ++j) v += counts8[(size_t)j * N + i];
        counts[i] = v;
    }
    sm[threadIdx.x] = v; __syncthreads();
    for (int off = 1; off < 256; off <<= 1) {
        int add = (threadIdx.x >= off) ? sm[threadIdx.x - off] : 0;
        __syncthreads();
        sm[threadIdx.x] += add;
        __syncthreads();
    }
    if (i < N) offs[i] = sm[threadIdx.x] - v;
    if (threadIdx.x == 255) partials[blockIdx.x] = sm[255];
}

__global__ void scan_add(int* __restrict__ offs, int* __restrict__ cursor,
                         const int* __restrict__ partials, int nb, int N) {
    __shared__ int sm[256];
    int t = threadIdx.x;
    sm[t] = (t < nb && t < blockIdx.x) ? partials[t] : 0;
    __syncthreads();
    for (int off = 128; off > 0; off >>= 1) {
        if (t < off) sm[t] += sm[t + off];
        __syncthreads();
    }
    int basev = sm[0];
    int i = blockIdx.x * 256 + t;
    if (i < N) {
        int v = offs[i] + basev;
        offs[i] = v;
        cursor[i] = v;
    }
}

// ---------------------------------------------------------------------------
// scatter_edges: put each edge into its dst-CSR slot as (src, dst).
// ---------------------------------------------------------------------------
__global__ void scatter_edges(const int* __restrict__ src, const int* __restrict__ dst,
                              int* __restrict__ cursor, int2* __restrict__ csr, int E) {
    int e = blockIdx.x * 256 + threadIdx.x;
    if (e < E) {
        int s = src[e], d = dst[e];
        int p = atomicAdd(&cursor[d], 1);
        csr[p] = make_int2(s, d);
    }
}

// ---------------------------------------------------------------------------
// edge_score (dst-sorted, pos-folded, raw-exp): iterate CSR slots p coalesced.
// |s| << 1 for this model, so exp(s) without max-subtraction is exact softmax
// after the global U/Z division. Writes e^s (f32 bits) into csr[p].y and
// accumulates Z with one atomicAdd per block. No online-max machinery.
// ---------------------------------------------------------------------------
__global__ __launch_bounds__(256, 4)
void edge_score(const ushort_t* __restrict__ P, const ushort_t* __restrict__ Q,
                const float* __restrict__ W2, const float* __restrict__ b2,
                int2* __restrict__ csr, float* __restrict__ Zg, int E) {
    __shared__ float wsh[128];
    __shared__ float zsh[4];
    int t = threadIdx.x;
    if (t < 128) wsh[t] = W2[t];
    __syncthreads();
    int w = t >> 6, lane = t & 63;
    int g = lane >> 4, c = lane & 15;
    float wv[8];
#pragma unroll
    for (int j = 0; j < 8; ++j) wv[j] = wsh[c * 8 + j];
    float b2v = b2[0];
    int base = blockIdx.x * 128 + w * 32;
    float zacc = 0.f;
#pragma unroll
    for (int ch = 0; ch < 2; ++ch) {
        int sa[4], da[4];
        uint4 pr[4], qr[4];
        // 1) CSR entries (coalesced; 16-lane broadcast per edge)
#pragma unroll
        for (int it = 0; it < 4; ++it) {
            int p = base + ch * 16 + it * 4 + g;
            int pp = (p < E) ? p : (E - 1);
            int2 v = csr[pp];
            sa[it] = v.x; da[it] = v.y;
        }
        // 2) issue the 4 random Q gathers first (latency-critical), then P
#pragma unroll
        for (int it = 0; it < 4; ++it)
            qr[it] = *(const uint4*)&Q[(size_t)sa[it] * 128 + c * 8];
#pragma unroll
        for (int it = 0; it < 4; ++it)
            pr[it] = *(const uint4*)&P[(size_t)da[it] * 128 + c * 8];
        // 3) compute + coalesced e^s write-back
#pragma unroll
        for (int it = 0; it < 4; ++it) {
            unsigned pw[4] = {pr[it].x, pr[it].y, pr[it].z, pr[it].w};
            unsigned qw[4] = {qr[it].x, qr[it].y, qr[it].z, qr[it].w};
            float v = 0.f;
#pragma unroll
            for (int jj = 0; jj < 4; ++jj) {
                float pe = bflo(pw[jj]) + bflo(qw[jj]);
                float po = bfhi(pw[jj]) + bfhi(qw[jj]);
                v += fmaxf(pe, 0.f) * wv[2 * jj] + fmaxf(po, 0.f) * wv[2 * jj + 1];
            }
#pragma unroll
            for (int off = 1; off < 16; off <<= 1) v += __shfl_xor(v, off, 64);
            int p = base + ch * 16 + it * 4 + g;
            if (c == 0 && p < E) {
                float ev = __expf(v + b2v);
                csr[p] = make_int2(sa[it], __float_as_int(ev));
                zacc += ev;
            }
        }
    }
    // block Z: butterfly (c!=0 lanes hold 0) + one atomic per block
    float zv = (c == 0) ? zacc : 0.f;
#pragma unroll
    for (int off = 1; off < 64; off <<= 1) zv += __shfl_xor(zv, off, 64);
    if (lane == 0) zsh[w] = zv;
    __syncthreads();
    if (t == 0) atomicAdd(Zg, zsh[0] + zsh[1] + zsh[2] + zsh[3]);
}

// ---------------------------------------------------------------------------
// gather_head: blocks [0,nbG): gather+upd, att = stored e^s * (1/Z) — no exp
// in the gather loop. Blocks [nbG,..): fused prediction heads.
// ---------------------------------------------------------------------------
__global__ void gather_head(const ushort_t* __restrict__ hb, const int2* __restrict__ csr,
                            const int* __restrict__ offs, const int* __restrict__ deg,
                            const float* __restrict__ Zg,
                            const ushort_t* __restrict__ Wub, const float* __restrict__ bu,
                            float* __restrict__ molf, int N, int nbG,
                            const float* __restrict__ rx, const float* __restrict__ tx,
                            const ushort_t* __restrict__ Wnb, const float* __restrict__ bn,
                            const ushort_t* __restrict__ Wy1b, const float* __restrict__ by1,
                            const float* __restrict__ Wy2, const float* __restrict__ by2,
                            const ushort_t* __restrict__ Wa1b, const float* __restrict__ ba1,
                            const float* __restrict__ Wa2, const float* __restrict__ ba2,
                            float* __restrict__ out, int nb1, int NR, int NT) {
    int t = threadIdx.x;
    int w = t >> 6, lane = t & 63;
    int c = lane & 15, q = lane >> 4;

    if (blockIdx.x < nbG) {
        // ------------------ gather + upd ------------------
        __shared__ ushort_t ldsA[16 * 136];
        float inv = 1.f / Zg[0];

        int g = lane >> 4;
        int r0 = blockIdx.x * 16;
#pragma unroll
        for (int i = 0; i < 4; ++i) {
            int node = r0 + w * 4 + i;
            float a[8] = {0.f, 0.f, 0.f, 0.f, 0.f, 0.f, 0.f, 0.f};
            if (node < N) {
                int start = offs[node], d = deg[node];
                int k = g;
                for (; k + 4 < d; k += 8) {   // 2 edges in flight per quarter-wave
                    int2 v0 = csr[start + k];
                    int2 v1 = csr[start + k + 4];
                    uint4 h0 = *(const uint4*)&hb[(size_t)v0.x * 128 + c * 8];
                    uint4 h1 = *(const uint4*)&hb[(size_t)v1.x * 128 + c * 8];
                    float at0 = __int_as_float(v0.y) * inv;
                    float at1 = __int_as_float(v1.y) * inv;
                    a[0] += bflo(h0.x) * at0; a[1] += bfhi(h0.x) * at0;
                    a[2] += bflo(h0.y) * at0; a[3] += bfhi(h0.y) * at0;
                    a[4] += bflo(h0.z) * at0; a[5] += bfhi(h0.z) * at0;
                    a[6] += bflo(h0.w) * at0; a[7] += bfhi(h0.w) * at0;
                    a[0] += bflo(h1.x) * at1; a[1] += bfhi(h1.x) * at1;
                    a[2] += bflo(h1.y) * at1; a[3] += bfhi(h1.y) * at1;
                    a[4] += bflo(h1.z) * at1; a[5] += bfhi(h1.z) * at1;
                    a[6] += bflo(h1.w) * at1; a[7] += bfhi(h1.w) * at1;
                }
                if (k < d) {
                    int2 v0 = csr[start + k];
                    uint4 h0 = *(const uint4*)&hb[(size_t)v0.x * 128 + c * 8];
                    float at0 = __int_as_float(v0.y) * inv;
                    a[0] += bflo(h0.x) * at0; a[1] += bfhi(h0.x) * at0;
                    a[2] += bflo(h0.y) * at0; a[3] += bfhi(h0.y) * at0;
                    a[4] += bflo(h0.z) * at0; a[5] += bfhi(h0.z) * at0;
                    a[6] += bflo(h0.w) * at0; a[7] += bfhi(h0.w) * at0;
                }
            }
#pragma unroll
            for (int j = 0; j < 8; ++j) {
                a[j] += __shfl_xor(a[j], 16, 64);
                a[j] += __shfl_xor(a[j], 32, 64);
            }
            if (g == 0) {
                uint4 pk;
                pk.x = f2bf(a[0]) | ((unsigned)f2bf(a[1]) << 16);
                pk.y = f2bf(a[2]) | ((unsigned)f2bf(a[3]) << 16);
                pk.z = f2bf(a[4]) | ((unsigned)f2bf(a[5]) << 16);
                pk.w = f2bf(a[6]) | ((unsigned)f2bf(a[7]) << 16);
                *(uint4*)&ldsA[(w * 4 + i) * 136 + c * 8] = pk;
            }
        }
        __syncthreads();
        int ntA = w, ntB = w + 4;
        f32x4 acc0 = {0.f, 0.f, 0.f, 0.f}, acc1 = acc0;
#pragma unroll
        for (int kt = 0; kt < 4; ++kt) {
            s16x8 av = *(const s16x8*)&ldsA[c * 136 + kt * 32 + q * 8];
            s16x8 b0 = *(const s16x8*)&Wub[((ntA * 4 + kt) * 64 + lane) * 8];
            s16x8 b1 = *(const s16x8*)&Wub[((ntB * 4 + kt) * 64 + lane) * 8];
            acc0 = __builtin_amdgcn_mfma_f32_16x16x32_bf16(av, b0, acc0, 0, 0, 0);
            acc1 = __builtin_amdgcn_mfma_f32_16x16x32_bf16(av, b1, acc1, 0, 0, 0);
        }
        float bi0 = bu[ntA * 16 + c], bi1 = bu[ntB * 16 + c];
#pragma unroll
        for (int r = 0; r < 4; ++r) {
            int row = r0 + q * 4 + r;
            if (row < N) {
                molf[(size_t)row * 128 + ntA * 16 + c] = acc0[r] + bi0;
                molf[(size_t)row * 128 + ntB * 16 + c] = acc1[r] + bi1;
            }
        }
    } else {
        // ------------------ prediction heads ------------------
        __shared__ ushort_t ldsX[16 * 72];
        __shared__ ushort_t ldsB[16 * 136];
        __shared__ float part[64];
        int blk = blockIdx.x - nbG;
        const float* x; const ushort_t* W1b; const float* b1; const float* W2; const float* b2;
        float* o; int r0, nrows;
        if (blk < nb1) { x = rx; W1b = Wy1b; b1 = by1; W2 = Wy2; b2 = by2; o = out; r0 = blk * 16; nrows = NR; }
        else { x = tx; W1b = Wa1b; b1 = ba1; W2 = Wa2; b2 = ba2; o = out + NR; r0 = (blk - nb1) * 16; nrows = NT; }
        {
            int row = t >> 4, c4 = (t & 15) * 4;
            float4 v = *(const float4*)&x[(size_t)(r0 + row) * 64 + c4];
            uint2 pk;
            pk.x = f2bf(v.x) | ((unsigned)f2bf(v.y) << 16);
            pk.y = f2bf(v.z) | ((unsigned)f2bf(v.w) << 16);
            *(uint2*)&ldsX[row * 72 + c4] = pk;
        }
        __syncthreads();
        {
            int ntA = w, ntB = w + 4;
            f32x4 acc0 = {0.f, 0.f, 0.f, 0.f}, acc1 = acc0;
#pragma unroll
            for (int kt = 0; kt < 2; ++kt) {
                s16x8 a = *(const s16x8*)&ldsX[c * 72 + kt * 32 + q * 8];
                s16x8 b0 = *(const s16x8*)&Wnb[((ntA * 2 + kt) * 64 + lane) * 8];
                s16x8 b1v = *(const s16x8*)&Wnb[((ntB * 2 + kt) * 64 + lane) * 8];
                acc0 = __builtin_amdgcn_mfma_f32_16x16x32_bf16(a, b0, acc0, 0, 0, 0);
                acc1 = __builtin_amdgcn_mfma_f32_16x16x32_bf16(a, b1v, acc1, 0, 0, 0);
            }
            float bi0 = bn[ntA * 16 + c], bi1 = bn[ntB * 16 + c];
#pragma unroll
            for (int r = 0; r < 4; ++r) {
                int row = q * 4 + r;
                ldsB[row * 136 + ntA * 16 + c] = f2bf(acc0[r] + bi0);
                ldsB[row * 136 + ntB * 16 + c] = f2bf(acc1[r] + bi1);
            }
        }
        __syncthreads();
        {
            f32x4 acc = {0.f, 0.f, 0.f, 0.f};
#pragma unroll
            for (int kt = 0; kt < 4; ++kt) {
                s16x8 a = *(const s16x8*)&ldsB[c * 136 + kt * 32 + q * 8];
                s16x8 b0 = *(const s16x8*)&W1b[((w * 4 + kt) * 64 + lane) * 8];
                acc = __builtin_amdgcn_mfma_f32_16x16x32_bf16(a, b0, acc, 0, 0, 0);
            }
            float bi = b1[w * 16 + c], w2v = W2[w * 16 + c];
#pragma unroll
            for (int r = 0; r < 4; ++r) {
                float u = fmaxf(acc[r] + bi, 0.f) * w2v;
#pragma unroll
                for (int mm = 1; mm < 16; mm <<= 1) u += __shfl_xor(u, mm, 64);
                if (c == 0) part[w * 16 + q * 4 + r] = u;
            }
        }
        __syncthreads();
        if (t < 16) {
            int row = r0 + t;
            if (row < nrows)
                o[row] = part[t] + part[16 + t] + part[32 + t] + part[48 + t] + b2[0];
        }
    }
}

extern "C" void kernel_launch(void* const* d_in, const int* in_sizes, int n_in,
                              void* d_out, int out_size, void* d_ws, size_t ws_size,
                              hipStream_t stream) {
    const float* mol_x      = (const float*)d_in[0];
    const float* pos        = (const float*)d_in[1];
    const float* reaction_x = (const float*)d_in[2];
    const float* target_x   = (const float*)d_in[3];
    const int*   ei         = (const int*)d_in[4];
    const float* W_node = (const float*)d_in[5];
    const float* b_node = (const float*)d_in[6];
    const float* W_att1 = (const float*)d_in[7];
    const float* b_att1 = (const float*)d_in[8];
    const float* W_att2 = (const float*)d_in[9];
    const float* b_att2 = (const float*)d_in[10];
    const float* W_upd  = (const float*)d_in[11];
    const float* b_upd  = (const float*)d_in[12];
    const float* Wy1 = (const float*)d_in[13];
    const float* by1 = (const float*)d_in[14];
    const float* Wy2 = (const float*)d_in[15];
    const float* by2 = (const float*)d_in[16];
    const float* Wa1 = (const float*)d_in[17];
    const float* ba1 = (const float*)d_in[18];
    const float* Wa2 = (const float*)d_in[19];
    const float* ba2 = (const float*)d_in[20];

    int N  = in_sizes[0] / 64;
    int E  = in_sizes[4] / 2;
    int NR = in_sizes[2] / 64;
    int NT = in_sizes[3] / 64;

    float* out = (float*)d_out;

    int nbE = (E + 127) / 128;   // edge_score blocks
    int nbG = (N + 15) / 16;     // gather blocks
    int nbH = (NR + NT) / 16;    // head blocks

    // ws layout
    char* wp = (char*)d_ws;
    ushort_t* hb = (ushort_t*)wp;  wp += (size_t)N * 128 * 2;
    ushort_t* Qb = (ushort_t*)wp;  wp += (size_t)N * 128 * 2;
    float* Zg    = (float*)wp;     wp += 256;
    int* counts8 = (int*)wp;       wp += (size_t)8 * N * 4;
    int* counts  = (int*)wp;       wp += (size_t)N * 4;
    int* offs    = (int*)wp;       wp += (size_t)N * 4;
    int* cursor  = (int*)wp;       wp += (size_t)N * 4;
    int* partials= (int*)wp;       wp += 256 * 4;
    int2* csr    = (int2*)wp;      wp += (size_t)E * 8;
    ushort_t* Wnb  = (ushort_t*)wp; wp += 8192 * 2;
    ushort_t* W1tb = (ushort_t*)wp; wp += 16384 * 2;
    ushort_t* W1mb = (ushort_t*)wp; wp += 16384 * 2;
    ushort_t* Wub  = (ushort_t*)wp; wp += 16384 * 2;
    ushort_t* Wy1b = (ushort_t*)wp; wp += 8192 * 2;
    ushort_t* Wa1b = (ushort_t*)wp; wp += 8192 * 2;
    // P lives in the mol_feats output region (dead before gather writes it)
    ushort_t* Pb = (ushort_t*)(out + NR + NT);
    float* molf  = out + NR + NT;

    const int* srcp = ei;
    const int* dstp = ei + E;
    int nbN = (N + 255) / 256;
    int nbS = (E + 255) / 256;

    convert_w<<<nbN, 256, 0, stream>>>(W_node, W_att1, W_upd, Wy1, Wa1,
                                       Wnb, W1tb, W1mb, Wub, Wy1b, Wa1b,
                                       counts8, Zg, N);
    encode_pq<<<(N + 15) / 16, 256, 0, stream>>>(mol_x, Wnb, b_node, W1tb, W1mb, b_att1,
                                                 W_att1 + 256 * 128, pos,
                                                 hb, Pb, Qb, dstp, counts8, N, E);
    scan1<<<nbN, 256, 0, stream>>>(counts8, counts, offs, partials, N);
    scan_add<<<nbN, 256, 0, stream>>>(offs, cursor, partials, nbN, N);
    scatter_edges<<<nbS, 256, 0, stream>>>(srcp, dstp, cursor, csr, E);
    edge_score<<<nbE, 256, 0, stream>>>(Pb, Qb, W_att2, b_att2,
                                        csr, Zg, E);
    gather_head<<<nbG + nbH, 256, 0, stream>>>(hb, csr, offs, counts, Zg,
                                               Wub, b_upd, molf, N, nbG,
                                               reaction_x, target_x, Wnb, b_node,
                                               Wy1b, by1, Wy2, by2, Wa1b, ba1, Wa2, ba2,
                                               out, NR / 16, NR, NT);
}

// Round 8
// 224.379 us; speedup vs baseline: 1.3783x; 1.1176x over previous
//
#include <hip/hip_runtime.h>
#include <hip/hip_bf16.h>

typedef unsigned short ushort_t;
typedef __attribute__((ext_vector_type(8))) short s16x8;
typedef __attribute__((ext_vector_type(4))) float f32x4;

__device__ inline unsigned short f2bf(float x) {
    unsigned u = __float_as_uint(x);
    return (unsigned short)((u + 0x7FFFu + ((u >> 16) & 1u)) >> 16);
}
__device__ inline float bflo(unsigned u) { return __uint_as_float(u << 16); }
__device__ inline float bfhi(unsigned u) { return __uint_as_float(u & 0xffff0000u); }

// ---------------------------------------------------------------------------
// convert_w: pack weights into MFMA B-fragment order (bf16). Zeroes counts8.
// ---------------------------------------------------------------------------
__device__ inline void pack_one(const float* __restrict__ W, int K, int N,
                                ushort_t* __restrict__ dst, int g) {
    int KT = K / 32;
    int nt = g / (KT * 64);
    int rem = g % (KT * 64);
    int kt = rem / 64, lane = rem % 64;
    int n = nt * 16 + (lane & 15);
    int kbase = kt * 32 + ((lane >> 4) << 3);
    ushort_t tmp[8];
#pragma unroll
    for (int j = 0; j < 8; ++j) tmp[j] = f2bf(W[(size_t)(kbase + j) * N + n]);
    uint4 pk;
    pk.x = tmp[0] | ((unsigned)tmp[1] << 16);
    pk.y = tmp[2] | ((unsigned)tmp[3] << 16);
    pk.z = tmp[4] | ((unsigned)tmp[5] << 16);
    pk.w = tmp[6] | ((unsigned)tmp[7] << 16);
    *(uint4*)&dst[(size_t)g * 8] = pk;
}

__global__ void convert_w(const float* __restrict__ Wn, const float* __restrict__ W1,
                          const float* __restrict__ Wu, const float* __restrict__ Wy1,
                          const float* __restrict__ Wa1,
                          ushort_t* __restrict__ Wnb, ushort_t* __restrict__ W1tb,
                          ushort_t* __restrict__ W1mb, ushort_t* __restrict__ Wub,
                          ushort_t* __restrict__ Wy1b, ushort_t* __restrict__ Wa1b,
                          int* __restrict__ counts8, int N) {
    int t = blockIdx.x * 256 + threadIdx.x;
    if (t < 1024)       pack_one(Wn, 64, 128, Wnb, t);
    else if (t < 3072)  pack_one(W1, 128, 128, W1tb, t - 1024);
    else if (t < 5120)  pack_one(W1 + 128 * 128, 128, 128, W1mb, t - 3072);
    else if (t < 7168)  pack_one(Wu, 128, 128, Wub, t - 5120);
    else if (t < 8192)  pack_one(Wy1, 128, 64, Wy1b, t - 7168);
    else if (t < 9216)  pack_one(Wa1, 128, 64, Wa1b, t - 8192);
    int stride = gridDim.x * 256;
    for (int i = t; i < 8 * N; i += stride) counts8[i] = 0;
}

// ---------------------------------------------------------------------------
// encode_pq: 16-row M-tile per block, 4 waves split N-tiles. pos folded into
// P'/Q'. dst histogram at the end, 8-way privatized.
// ---------------------------------------------------------------------------
__global__ void encode_pq(const float* __restrict__ x, const ushort_t* __restrict__ Wnb,
                          const float* __restrict__ bn, const ushort_t* __restrict__ W1tb,
                          const ushort_t* __restrict__ W1mb, const float* __restrict__ b1,
                          const float* __restrict__ Wd, const float* __restrict__ pos,
                          ushort_t* __restrict__ hb, ushort_t* __restrict__ P,
                          ushort_t* __restrict__ Q, const int* __restrict__ dst,
                          int* __restrict__ counts8, int nrows, int E) {
    __shared__ ushort_t ldsH[16 * 136];
    __shared__ float ldsWd[384];
    int t = threadIdx.x;
    for (int i = t; i < 384; i += 256) ldsWd[i] = Wd[i];
    int w = t >> 6, lane = t & 63;
    int c = lane & 15, q = lane >> 4;
    int r0 = blockIdx.x * 16;
    int rowA = r0 + c; if (rowA >= nrows) rowA = nrows - 1;

    s16x8 xa[2];
#pragma unroll
    for (int kt = 0; kt < 2; ++kt) {
        const float* xp = &x[(size_t)rowA * 64 + kt * 32 + q * 8];
        float4 v0 = *(const float4*)xp;
        float4 v1 = *(const float4*)(xp + 4);
        s16x8 a;
        a[0] = (short)f2bf(v0.x); a[1] = (short)f2bf(v0.y);
        a[2] = (short)f2bf(v0.z); a[3] = (short)f2bf(v0.w);
        a[4] = (short)f2bf(v1.x); a[5] = (short)f2bf(v1.y);
        a[6] = (short)f2bf(v1.z); a[7] = (short)f2bf(v1.w);
        xa[kt] = a;
    }
#pragma unroll
    for (int half = 0; half < 2; ++half) {
        int nt = w + half * 4;
        f32x4 acc = {0.f, 0.f, 0.f, 0.f};
#pragma unroll
        for (int kt = 0; kt < 2; ++kt) {
            s16x8 b = *(const s16x8*)&Wnb[((nt * 2 + kt) * 64 + lane) * 8];
            acc = __builtin_amdgcn_mfma_f32_16x16x32_bf16(xa[kt], b, acc, 0, 0, 0);
        }
        float bi = bn[nt * 16 + c];
#pragma unroll
        for (int r = 0; r < 4; ++r) {
            int row = r0 + q * 4 + r;
            ushort_t hv = f2bf(acc[r] + bi);
            ldsH[(q * 4 + r) * 136 + nt * 16 + c] = hv;
            if (row < nrows) hb[(size_t)row * 128 + nt * 16 + c] = hv;
        }
    }
    __syncthreads();
    s16x8 ha[4];
#pragma unroll
    for (int kt = 0; kt < 4; ++kt)
        ha[kt] = *(const s16x8*)&ldsH[c * 136 + kt * 32 + q * 8];
    float prx[4], pry[4], prz[4];
#pragma unroll
    for (int r = 0; r < 4; ++r) {
        int row = r0 + q * 4 + r;
        int rowc = (row < nrows) ? row : (nrows - 1);
        prx[r] = pos[rowc * 3];
        pry[r] = pos[rowc * 3 + 1];
        prz[r] = pos[rowc * 3 + 2];
    }
#pragma unroll
    for (int half = 0; half < 2; ++half) {
        int nt = w + half * 4;
        f32x4 pa = {0.f, 0.f, 0.f, 0.f}, qa = pa;
#pragma unroll
        for (int kt = 0; kt < 4; ++kt) {
            s16x8 bp = *(const s16x8*)&W1tb[((nt * 4 + kt) * 64 + lane) * 8];
            s16x8 bq = *(const s16x8*)&W1mb[((nt * 4 + kt) * 64 + lane) * 8];
            pa = __builtin_amdgcn_mfma_f32_16x16x32_bf16(ha[kt], bp, pa, 0, 0, 0);
            qa = __builtin_amdgcn_mfma_f32_16x16x32_bf16(ha[kt], bq, qa, 0, 0, 0);
        }
        int col = nt * 16 + c;
        float bi = b1[col];
        float wd0 = ldsWd[col], wd1 = ldsWd[128 + col], wd2 = ldsWd[256 + col];
#pragma unroll
        for (int r = 0; r < 4; ++r) {
            int row = r0 + q * 4 + r;
            if (row < nrows) {
                float pd = prx[r] * wd0 + pry[r] * wd1 + prz[r] * wd2;
                P[(size_t)row * 128 + col] = f2bf(pa[r] + bi + pd);
                Q[(size_t)row * 128 + col] = f2bf(qa[r] - pd);
            }
        }
    }
    int* myc = counts8 + (size_t)(blockIdx.x & 7) * nrows;
    for (int e = blockIdx.x * 256 + t; e < E; e += gridDim.x * 256)
        atomicAdd(&myc[dst[e]], 1);
}

// ---------------------------------------------------------------------------
// CSR scan: scan1 (merges 8 privatized bins -> counts) + scan_add
// ---------------------------------------------------------------------------
__global__ void scan1(const int* __restrict__ counts8, int* __restrict__ counts,
                      int* __restrict__ offs, int* __restrict__ partials, int N) {
    __shared__ int sm[256];
    int i = blockIdx.x * 256 + threadIdx.x;
    int v = 0;
    if (i < N) {
#pragma unroll
        for (int j = 0; j < 8; ++j) v += counts8[(size_t)j * N + i];
        counts[i] = v;
    }
    sm[threadIdx.x] = v; __syncthreads();
    for (int off = 1; off < 256; off <<= 1) {
        int add = (threadIdx.x >= off) ? sm[threadIdx.x - off] : 0;
        __syncthreads();
        sm[threadIdx.x] += add;
        __syncthreads();
    }
    if (i < N) offs[i] = sm[threadIdx.x] - v;
    if (threadIdx.x == 255) partials[blockIdx.x] = sm[255];
}

__global__ void scan_add(int* __restrict__ offs, int* __restrict__ cursor,
                         const int* __restrict__ partials, int nb, int N) {
    __shared__ int sm[256];
    int t = threadIdx.x;
    sm[t] = (t < nb && t < blockIdx.x) ? partials[t] : 0;
    __syncthreads();
    for (int off = 128; off > 0; off >>= 1) {
        if (t < off) sm[t] += sm[t + off];
        __syncthreads();
    }
    int basev = sm[0];
    int i = blockIdx.x * 256 + t;
    if (i < N) {
        int v = offs[i] + basev;
        offs[i] = v;
        cursor[i] = v;
    }
}

// ---------------------------------------------------------------------------
// scatter_edges: put each edge into its dst-CSR slot as (src, dst).
// ---------------------------------------------------------------------------
__global__ void scatter_edges(const int* __restrict__ src, const int* __restrict__ dst,
                              int* __restrict__ cursor, int2* __restrict__ csr, int E) {
    int e = blockIdx.x * 256 + threadIdx.x;
    if (e < E) {
        int s = src[e], d = dst[e];
        int p = atomicAdd(&cursor[d], 1);
        csr[p] = make_int2(s, d);
    }
}

// ---------------------------------------------------------------------------
// edge_score (dst-sorted, pos-folded, raw-exp): writes e^s into csr[p].y.
// Per-block Z partial stored to rede[block] (NO same-address global atomic —
// round-7's single-Zg atomicAdd ping-ponged one line across all 8 XCDs).
// sched_barrier(0) pins the 8-row-load cluster before the MLP so the loads
// stay co-live (round-7 compiled to 36 VGPR = serialized gathers).
// ---------------------------------------------------------------------------
__global__ __launch_bounds__(256, 4)
void edge_score(const ushort_t* __restrict__ P, const ushort_t* __restrict__ Q,
                const float* __restrict__ W2, const float* __restrict__ b2,
                int2* __restrict__ csr, float* __restrict__ rede, int E) {
    __shared__ float wsh[128];
    __shared__ float zsh[4];
    int t = threadIdx.x;
    if (t < 128) wsh[t] = W2[t];
    __syncthreads();
    int w = t >> 6, lane = t & 63;
    int g = lane >> 4, c = lane & 15;
    float wv[8];
#pragma unroll
    for (int j = 0; j < 8; ++j) wv[j] = wsh[c * 8 + j];
    float b2v = b2[0];
    int base = blockIdx.x * 128 + w * 32;
    float zacc = 0.f;
#pragma unroll
    for (int ch = 0; ch < 2; ++ch) {
        int sa[4], da[4];
        uint4 pr[4], qr[4];
        // 1) CSR entries (coalesced; 16-lane broadcast per edge)
#pragma unroll
        for (int it = 0; it < 4; ++it) {
            int p = base + ch * 16 + it * 4 + g;
            int pp = (p < E) ? p : (E - 1);
            int2 v = csr[pp];
            sa[it] = v.x; da[it] = v.y;
        }
        // 2) issue all 8 row gathers back-to-back; keep them co-live
#pragma unroll
        for (int it = 0; it < 4; ++it)
            qr[it] = *(const uint4*)&Q[(size_t)sa[it] * 128 + c * 8];
#pragma unroll
        for (int it = 0; it < 4; ++it)
            pr[it] = *(const uint4*)&P[(size_t)da[it] * 128 + c * 8];
        __builtin_amdgcn_sched_barrier(0);
        // 3) compute + coalesced e^s write-back
#pragma unroll
        for (int it = 0; it < 4; ++it) {
            unsigned pw[4] = {pr[it].x, pr[it].y, pr[it].z, pr[it].w};
            unsigned qw[4] = {qr[it].x, qr[it].y, qr[it].z, qr[it].w};
            float v = 0.f;
#pragma unroll
            for (int jj = 0; jj < 4; ++jj) {
                float pe = bflo(pw[jj]) + bflo(qw[jj]);
                float po = bfhi(pw[jj]) + bfhi(qw[jj]);
                v += fmaxf(pe, 0.f) * wv[2 * jj] + fmaxf(po, 0.f) * wv[2 * jj + 1];
            }
#pragma unroll
            for (int off = 1; off < 16; off <<= 1) v += __shfl_xor(v, off, 64);
            int p = base + ch * 16 + it * 4 + g;
            if (c == 0 && p < E) {
                float ev = __expf(v + b2v);
                csr[p] = make_int2(sa[it], __float_as_int(ev));
                zacc += ev;
            }
        }
    }
    // block Z: butterfly (c!=0 lanes hold 0) + one plain store per block
    float zv = (c == 0) ? zacc : 0.f;
#pragma unroll
    for (int off = 1; off < 64; off <<= 1) zv += __shfl_xor(zv, off, 64);
    if (lane == 0) zsh[w] = zv;
    __syncthreads();
    if (t == 0) rede[blockIdx.x] = zsh[0] + zsh[1] + zsh[2] + zsh[3];
}

// ---------------------------------------------------------------------------
// reduce_z: single block sums per-block Z partials -> Zg[0] = 1/Z.
// ---------------------------------------------------------------------------
__global__ void reduce_z(const float* __restrict__ rede, float* __restrict__ Zg,
                         int nbE) {
    __shared__ float sm[256];
    int t = threadIdx.x;
    float z = 0.f;
    for (int i = t; i < nbE; i += 256) z += rede[i];
    sm[t] = z; __syncthreads();
    for (int off = 128; off > 0; off >>= 1) {
        if (t < off) sm[t] += sm[t + off];
        __syncthreads();
    }
    if (t == 0) Zg[0] = 1.f / sm[0];
}

// ---------------------------------------------------------------------------
// gather_head: blocks [0,nbG): gather+upd, att = stored e^s * inv — no exp
// in the gather loop. Blocks [nbG,..): fused prediction heads.
// ---------------------------------------------------------------------------
__global__ void gather_head(const ushort_t* __restrict__ hb, const int2* __restrict__ csr,
                            const int* __restrict__ offs, const int* __restrict__ deg,
                            const float* __restrict__ Zg,
                            const ushort_t* __restrict__ Wub, const float* __restrict__ bu,
                            float* __restrict__ molf, int N, int nbG,
                            const float* __restrict__ rx, const float* __restrict__ tx,
                            const ushort_t* __restrict__ Wnb, const float* __restrict__ bn,
                            const ushort_t* __restrict__ Wy1b, const float* __restrict__ by1,
                            const float* __restrict__ Wy2, const float* __restrict__ by2,
                            const ushort_t* __restrict__ Wa1b, const float* __restrict__ ba1,
                            const float* __restrict__ Wa2, const float* __restrict__ ba2,
                            float* __restrict__ out, int nb1, int NR, int NT) {
    int t = threadIdx.x;
    int w = t >> 6, lane = t & 63;
    int c = lane & 15, q = lane >> 4;

    if (blockIdx.x < nbG) {
        // ------------------ gather + upd ------------------
        __shared__ ushort_t ldsA[16 * 136];
        float inv = Zg[0];

        int g = lane >> 4;
        int r0 = blockIdx.x * 16;
#pragma unroll
        for (int i = 0; i < 4; ++i) {
            int node = r0 + w * 4 + i;
            float a[8] = {0.f, 0.f, 0.f, 0.f, 0.f, 0.f, 0.f, 0.f};
            if (node < N) {
                int start = offs[node], d = deg[node];
                int k = g;
                for (; k + 4 < d; k += 8) {   // 2 edges in flight per quarter-wave
                    int2 v0 = csr[start + k];
                    int2 v1 = csr[start + k + 4];
                    uint4 h0 = *(const uint4*)&hb[(size_t)v0.x * 128 + c * 8];
                    uint4 h1 = *(const uint4*)&hb[(size_t)v1.x * 128 + c * 8];
                    float at0 = __int_as_float(v0.y) * inv;
                    float at1 = __int_as_float(v1.y) * inv;
                    a[0] += bflo(h0.x) * at0; a[1] += bfhi(h0.x) * at0;
                    a[2] += bflo(h0.y) * at0; a[3] += bfhi(h0.y) * at0;
                    a[4] += bflo(h0.z) * at0; a[5] += bfhi(h0.z) * at0;
                    a[6] += bflo(h0.w) * at0; a[7] += bfhi(h0.w) * at0;
                    a[0] += bflo(h1.x) * at1; a[1] += bfhi(h1.x) * at1;
                    a[2] += bflo(h1.y) * at1; a[3] += bfhi(h1.y) * at1;
                    a[4] += bflo(h1.z) * at1; a[5] += bfhi(h1.z) * at1;
                    a[6] += bflo(h1.w) * at1; a[7] += bfhi(h1.w) * at1;
                }
                if (k < d) {
                    int2 v0 = csr[start + k];
                    uint4 h0 = *(const uint4*)&hb[(size_t)v0.x * 128 + c * 8];
                    float at0 = __int_as_float(v0.y) * inv;
                    a[0] += bflo(h0.x) * at0; a[1] += bfhi(h0.x) * at0;
                    a[2] += bflo(h0.y) * at0; a[3] += bfhi(h0.y) * at0;
                    a[4] += bflo(h0.z) * at0; a[5] += bfhi(h0.z) * at0;
                    a[6] += bflo(h0.w) * at0; a[7] += bfhi(h0.w) * at0;
                }
            }
#pragma unroll
            for (int j = 0; j < 8; ++j) {
                a[j] += __shfl_xor(a[j], 16, 64);
                a[j] += __shfl_xor(a[j], 32, 64);
            }
            if (g == 0) {
                uint4 pk;
                pk.x = f2bf(a[0]) | ((unsigned)f2bf(a[1]) << 16);
                pk.y = f2bf(a[2]) | ((unsigned)f2bf(a[3]) << 16);
                pk.z = f2bf(a[4]) | ((unsigned)f2bf(a[5]) << 16);
                pk.w = f2bf(a[6]) | ((unsigned)f2bf(a[7]) << 16);
                *(uint4*)&ldsA[(w * 4 + i) * 136 + c * 8] = pk;
            }
        }
        __syncthreads();
        int ntA = w, ntB = w + 4;
        f32x4 acc0 = {0.f, 0.f, 0.f, 0.f}, acc1 = acc0;
#pragma unroll
        for (int kt = 0; kt < 4; ++kt) {
            s16x8 av = *(const s16x8*)&ldsA[c * 136 + kt * 32 + q * 8];
            s16x8 b0 = *(const s16x8*)&Wub[((ntA * 4 + kt) * 64 + lane) * 8];
            s16x8 b1 = *(const s16x8*)&Wub[((ntB * 4 + kt) * 64 + lane) * 8];
            acc0 = __builtin_amdgcn_mfma_f32_16x16x32_bf16(av, b0, acc0, 0, 0, 0);
            acc1 = __builtin_amdgcn_mfma_f32_16x16x32_bf16(av, b1, acc1, 0, 0, 0);
        }
        float bi0 = bu[ntA * 16 + c], bi1 = bu[ntB * 16 + c];
#pragma unroll
        for (int r = 0; r < 4; ++r) {
            int row = r0 + q * 4 + r;
            if (row < N) {
                molf[(size_t)row * 128 + ntA * 16 + c] = acc0[r] + bi0;
                molf[(size_t)row * 128 + ntB * 16 + c] = acc1[r] + bi1;
            }
        }
    } else {
        // ------------------ prediction heads ------------------
        __shared__ ushort_t ldsX[16 * 72];
        __shared__ ushort_t ldsB[16 * 136];
        __shared__ float part[64];
        int blk = blockIdx.x - nbG;
        const float* x; const ushort_t* W1b; const float* b1; const float* W2; const float* b2;
        float* o; int r0, nrows;
        if (blk < nb1) { x = rx; W1b = Wy1b; b1 = by1; W2 = Wy2; b2 = by2; o = out; r0 = blk * 16; nrows = NR; }
        else { x = tx; W1b = Wa1b; b1 = ba1; W2 = Wa2; b2 = ba2; o = out + NR; r0 = (blk - nb1) * 16; nrows = NT; }
        {
            int row = t >> 4, c4 = (t & 15) * 4;
            float4 v = *(const float4*)&x[(size_t)(r0 + row) * 64 + c4];
            uint2 pk;
            pk.x = f2bf(v.x) | ((unsigned)f2bf(v.y) << 16);
            pk.y = f2bf(v.z) | ((unsigned)f2bf(v.w) << 16);
            *(uint2*)&ldsX[row * 72 + c4] = pk;
        }
        __syncthreads();
        {
            int ntA = w, ntB = w + 4;
            f32x4 acc0 = {0.f, 0.f, 0.f, 0.f}, acc1 = acc0;
#pragma unroll
            for (int kt = 0; kt < 2; ++kt) {
                s16x8 a = *(const s16x8*)&ldsX[c * 72 + kt * 32 + q * 8];
                s16x8 b0 = *(const s16x8*)&Wnb[((ntA * 2 + kt) * 64 + lane) * 8];
                s16x8 b1v = *(const s16x8*)&Wnb[((ntB * 2 + kt) * 64 + lane) * 8];
                acc0 = __builtin_amdgcn_mfma_f32_16x16x32_bf16(a, b0, acc0, 0, 0, 0);
                acc1 = __builtin_amdgcn_mfma_f32_16x16x32_bf16(a, b1v, acc1, 0, 0, 0);
            }
            float bi0 = bn[ntA * 16 + c], bi1 = bn[ntB * 16 + c];
#pragma unroll
            for (int r = 0; r < 4; ++r) {
                int row = q * 4 + r;
                ldsB[row * 136 + ntA * 16 + c] = f2bf(acc0[r] + bi0);
                ldsB[row * 136 + ntB * 16 + c] = f2bf(acc1[r] + bi1);
            }
        }
        __syncthreads();
        {
            f32x4 acc = {0.f, 0.f, 0.f, 0.f};
#pragma unroll
            for (int kt = 0; kt < 4; ++kt) {
                s16x8 a = *(const s16x8*)&ldsB[c * 136 + kt * 32 + q * 8];
                s16x8 b0 = *(const s16x8*)&W1b[((w * 4 + kt) * 64 + lane) * 8];
                acc = __builtin_amdgcn_mfma_f32_16x16x32_bf16(a, b0, acc, 0, 0, 0);
            }
            float bi = b1[w * 16 + c], w2v = W2[w * 16 + c];
#pragma unroll
            for (int r = 0; r < 4; ++r) {
                float u = fmaxf(acc[r] + bi, 0.f) * w2v;
#pragma unroll
                for (int mm = 1; mm < 16; mm <<= 1) u += __shfl_xor(u, mm, 64);
                if (c == 0) part[w * 16 + q * 4 + r] = u;
            }
        }
        __syncthreads();
        if (t < 16) {
            int row = r0 + t;
            if (row < nrows)
                o[row] = part[t] + part[16 + t] + part[32 + t] + part[48 + t] + b2[0];
        }
    }
}

extern "C" void kernel_launch(void* const* d_in, const int* in_sizes, int n_in,
                              void* d_out, int out_size, void* d_ws, size_t ws_size,
                              hipStream_t stream) {
    const float* mol_x      = (const float*)d_in[0];
    const float* pos        = (const float*)d_in[1];
    const float* reaction_x = (const float*)d_in[2];
    const float* target_x   = (const float*)d_in[3];
    const int*   ei         = (const int*)d_in[4];
    const float* W_node = (const float*)d_in[5];
    const float* b_node = (const float*)d_in[6];
    const float* W_att1 = (const float*)d_in[7];
    const float* b_att1 = (const float*)d_in[8];
    const float* W_att2 = (const float*)d_in[9];
    const float* b_att2 = (const float*)d_in[10];
    const float* W_upd  = (const float*)d_in[11];
    const float* b_upd  = (const float*)d_in[12];
    const float* Wy1 = (const float*)d_in[13];
    const float* by1 = (const float*)d_in[14];
    const float* Wy2 = (const float*)d_in[15];
    const float* by2 = (const float*)d_in[16];
    const float* Wa1 = (const float*)d_in[17];
    const float* ba1 = (const float*)d_in[18];
    const float* Wa2 = (const float*)d_in[19];
    const float* ba2 = (const float*)d_in[20];

    int N  = in_sizes[0] / 64;
    int E  = in_sizes[4] / 2;
    int NR = in_sizes[2] / 64;
    int NT = in_sizes[3] / 64;

    float* out = (float*)d_out;

    int nbE = (E + 127) / 128;   // edge_score blocks
    int nbG = (N + 15) / 16;     // gather blocks
    int nbH = (NR + NT) / 16;    // head blocks

    // ws layout
    char* wp = (char*)d_ws;
    ushort_t* hb = (ushort_t*)wp;  wp += (size_t)N * 128 * 2;
    ushort_t* Qb = (ushort_t*)wp;  wp += (size_t)N * 128 * 2;
    float* rede  = (float*)wp;     wp += (size_t)nbE * 4;
    float* Zg    = (float*)wp;     wp += 256;
    int* counts8 = (int*)wp;       wp += (size_t)8 * N * 4;
    int* counts  = (int*)wp;       wp += (size_t)N * 4;
    int* offs    = (int*)wp;       wp += (size_t)N * 4;
    int* cursor  = (int*)wp;       wp += (size_t)N * 4;
    int* partials= (int*)wp;       wp += 256 * 4;
    int2* csr    = (int2*)wp;      wp += (size_t)E * 8;
    ushort_t* Wnb  = (ushort_t*)wp; wp += 8192 * 2;
    ushort_t* W1tb = (ushort_t*)wp; wp += 16384 * 2;
    ushort_t* W1mb = (ushort_t*)wp; wp += 16384 * 2;
    ushort_t* Wub  = (ushort_t*)wp; wp += 16384 * 2;
    ushort_t* Wy1b = (ushort_t*)wp; wp += 8192 * 2;
    ushort_t* Wa1b = (ushort_t*)wp; wp += 8192 * 2;
    // P lives in the mol_feats output region (dead before gather writes it)
    ushort_t* Pb = (ushort_t*)(out + NR + NT);
    float* molf  = out + NR + NT;

    const int* srcp = ei;
    const int* dstp = ei + E;
    int nbN = (N + 255) / 256;
    int nbS = (E + 255) / 256;

    convert_w<<<nbN, 256, 0, stream>>>(W_node, W_att1, W_upd, Wy1, Wa1,
                                       Wnb, W1tb, W1mb, Wub, Wy1b, Wa1b,
                                       counts8, N);
    encode_pq<<<(N + 15) / 16, 256, 0, stream>>>(mol_x, Wnb, b_node, W1tb, W1mb, b_att1,
                                                 W_att1 + 256 * 128, pos,
                                                 hb, Pb, Qb, dstp, counts8, N, E);
    scan1<<<nbN, 256, 0, stream>>>(counts8, counts, offs, partials, N);
    scan_add<<<nbN, 256, 0, stream>>>(offs, cursor, partials, nbN, N);
    scatter_edges<<<nbS, 256, 0, stream>>>(srcp, dstp, cursor, csr, E);
    edge_score<<<nbE, 256, 0, stream>>>(Pb, Qb, W_att2, b_att2,
                                        csr, rede, E);
    reduce_z<<<1, 256, 0, stream>>>(rede, Zg, nbE);
    gather_head<<<nbG + nbH, 256, 0, stream>>>(hb, csr, offs, counts, Zg,
                                               Wub, b_upd, molf, N, nbG,
                                               reaction_x, target_x, Wnb, b_node,
                                               Wy1b, by1, Wy2, by2, Wa1b, ba1, Wa2, ba2,
                                               out, NR / 16, NR, NT);
}